// Round 15
// baseline (90.093 us; speedup 1.0000x reference)
//
#include <hip/hip_runtime.h>
#include <hip/hip_fp16.h>

#define NQ   13
#define DIM  8192
#define PI_F 3.14159265358979323846f
#define NT   256     // 4 waves/block; grid 512 -> 2 blocks/CU (grid-pinned)
#define NAMP 32      // amplitudes per thread (5-bit register window)

// fp16 state in LDS, pad +4 slots per 32: PAT0/PAT2 runs 16B-aligned for
// ds_*_b128, all patterns at the bank data floor (R13-verified).
__device__ __forceinline__ int lslot(int i) { return i + 4 * (i >> 5); }
#define NSLOT (DIM + 4 * (DIM >> 5))   // 9216 half2 slots = 36.9 KB

__device__ __forceinline__ int base0(int t) { return 36 * t; }
__device__ __forceinline__ int base2(int t, int g) { return 1152 * g + 4 * t + 4 * (t >> 3); }
__device__ __forceinline__ int slot1(int t, int j) { return 1152 * (t >> 5) + 36 * j + (t & 31); }

union F4H { float4 f; __half2 h[4]; };

__device__ __forceinline__ void rsincos(float x, float* s, float* c) {
  const float INV2PI = 0.15915494309189535f;
  const float TWOPI  = 6.283185307179586f;
  float r = x * INV2PI;
  r -= rintf(r);
  float ang = r * TWOPI;
  *s = __sinf(ang);
  *c = __cosf(ang);
}

// wave-local "barrier" (PAT0<->PAT1 both pin i-bits 11,12 to the wave id)
__device__ __forceinline__ void waveFence() {
  __builtin_amdgcn_wave_barrier();
  __threadfence_block();
  __builtin_amdgcn_wave_barrier();
}

// ---- fp32 helpers
__device__ __forceinline__ float2 f2fma(float s, float2 a, float2 b) {
  return make_float2(fmaf(s, a.x, b.x), fmaf(s, a.y, b.y));
}
__device__ __forceinline__ float2 f2add(float2 a, float2 b) {
  return make_float2(a.x + b.x, a.y + b.y);
}
__device__ __forceinline__ float2 f2sub(float2 a, float2 b) {
  return make_float2(a.x - b.x, a.y - b.y);
}
__device__ __forceinline__ float2 cphase(float2 v, float cs, float sn) {
  return make_float2(fmaf(cs, v.x, -sn * v.y), fmaf(cs, v.y, sn * v.x));
}
__device__ __forceinline__ float2 cmul(float2 a, float2 b) {
  return make_float2(fmaf(a.x, b.x, -a.y * b.y), fmaf(a.x, b.y, a.y * b.x));
}

template<int PAT>
__device__ __forceinline__ int ampIndex(int t, int j) {
  if constexpr (PAT == 0) return (t << 5) | j;
  else if constexpr (PAT == 1) return ((t >> 5) << 10) | (j << 5) | (t & 31);
  else return ((j >> 2) << 10) | (t << 2) | (j & 3);
}

// phase tree: s[j] = bias + sum over set bits of i(t,j) of w[bitpos]
template<int PAT>
__device__ __forceinline__ void buildTree(const float* __restrict__ w, float bias,
                                          int t, float* s) {
  float base = bias;
  if constexpr (PAT == 0) {
    #pragma unroll
    for (int k = 0; k < 8; k++) base += ((t >> k) & 1) ? w[5 + k] : 0.0f;
  } else {   // PAT2
    #pragma unroll
    for (int k = 0; k < 8; k++) base += ((t >> k) & 1) ? w[2 + k] : 0.0f;
  }
  constexpr int P[5] = { 0, 1,
                         (PAT == 0) ? 2 : 10,
                         (PAT == 0) ? 3 : 11,
                         (PAT == 0) ? 4 : 12 };
  s[0] = base;
  #pragma unroll
  for (int k = 0; k < 5; k++) {
    float wp = w[P[k]];
    #pragma unroll
    for (int m = 0; m < (1 << k); m++) s[m | (1 << k)] = s[m] + wp;
  }
}

// ---- fp32-register LDS access (b128 packed fp16 at the boundary)
__device__ __forceinline__ void loadA0f(const __half2* __restrict__ sAmp, int t, float2* amp) {
  const __half2* p = sAmp + base0(t);
  #pragma unroll
  for (int k = 0; k < 8; k++) {
    F4H u; u.f = *reinterpret_cast<const float4*>(p + 4 * k);
    #pragma unroll
    for (int c = 0; c < 4; c++) amp[4 * k + c] = __half22float2(u.h[c]);
  }
}
__device__ __forceinline__ void storeA0f(__half2* __restrict__ sAmp, int t, const float2* amp) {
  __half2* p = sAmp + base0(t);
  #pragma unroll
  for (int k = 0; k < 8; k++) {
    F4H u;
    #pragma unroll
    for (int c = 0; c < 4; c++) u.h[c] = __float22half2_rn(amp[4 * k + c]);
    *reinterpret_cast<float4*>(p + 4 * k) = u.f;
  }
}
__device__ __forceinline__ void loadA2f(const __half2* __restrict__ sAmp, int t, float2* amp) {
  #pragma unroll
  for (int g = 0; g < 8; g++) {
    F4H u; u.f = *reinterpret_cast<const float4*>(sAmp + base2(t, g));
    #pragma unroll
    for (int c = 0; c < 4; c++) amp[4 * g + c] = __half22float2(u.h[c]);
  }
}
__device__ __forceinline__ void storeA2f(__half2* __restrict__ sAmp, int t, const float2* amp) {
  #pragma unroll
  for (int g = 0; g < 8; g++) {
    F4H u;
    #pragma unroll
    for (int c = 0; c < 4; c++) u.h[c] = __float22half2_rn(amp[4 * g + c]);
    *reinterpret_cast<float4*>(sAmp + base2(t, g)) = u.f;
  }
}

// ---- fp16-register LDS access
__device__ __forceinline__ void loadA0h(const __half2* __restrict__ sAmp, int t, __half2* amp) {
  const __half2* p = sAmp + base0(t);
  #pragma unroll
  for (int k = 0; k < 8; k++) {
    F4H u; u.f = *reinterpret_cast<const float4*>(p + 4 * k);
    #pragma unroll
    for (int c = 0; c < 4; c++) amp[4 * k + c] = u.h[c];
  }
}
__device__ __forceinline__ void storeA0h(__half2* __restrict__ sAmp, int t, const __half2* amp) {
  __half2* p = sAmp + base0(t);
  #pragma unroll
  for (int k = 0; k < 8; k++) {
    F4H u;
    #pragma unroll
    for (int c = 0; c < 4; c++) u.h[c] = amp[4 * k + c];
    *reinterpret_cast<float4*>(p + 4 * k) = u.f;
  }
}
__device__ __forceinline__ void loadA1h(const __half2* __restrict__ sAmp, int t, __half2* amp) {
  #pragma unroll
  for (int j = 0; j < NAMP; j++) amp[j] = sAmp[slot1(t, j)];
}
__device__ __forceinline__ void storeA1h(__half2* __restrict__ sAmp, int t, const __half2* amp) {
  #pragma unroll
  for (int j = 0; j < NAMP; j++) sAmp[slot1(t, j)] = amp[j];
}

// ---- fp32 gate math
template<int KB>
__device__ __forceinline__ void fwht_bit(float2* amp) {
  #pragma unroll
  for (int j = 0; j < NAMP; j++) if (!(j & (1 << KB))) {
    int j1 = j | (1 << KB);
    float2 a0 = amp[j], a1 = amp[j1];
    amp[j]  = f2add(a0, a1);
    amp[j1] = f2sub(a0, a1);
  }
}
template<int KB>
__device__ __forceinline__ void applyRy(float2* amp, float ta, float sa) {
  #pragma unroll
  for (int j = 0; j < NAMP; j++) if (!(j & (1 << KB))) {
    int j1 = j | (1 << KB);
    amp[j]  = f2fma(-ta, amp[j1], amp[j]);
    amp[j1] = f2fma( sa, amp[j],  amp[j1]);
    amp[j]  = f2fma(-ta, amp[j1], amp[j]);
  }
}

// ---- fp16 packed gate math (v_pk_*_f16)
template<int KB>
__device__ __forceinline__ void fwht_bitH(__half2* amp) {
  #pragma unroll
  for (int j = 0; j < NAMP; j++) if (!(j & (1 << KB))) {
    int j1 = j | (1 << KB);
    __half2 a0 = amp[j], a1 = amp[j1];
    amp[j]  = __hadd2(a0, a1);
    amp[j1] = __hsub2(a0, a1);
  }
}
template<int KB>
__device__ __forceinline__ void applyRyH(__half2* amp, __half2 nta, __half2 sa) {
  #pragma unroll
  for (int j = 0; j < NAMP; j++) if (!(j & (1 << KB))) {
    int j1 = j | (1 << KB);
    amp[j]  = __hfma2(nta, amp[j1], amp[j]);
    amp[j1] = __hfma2(sa,  amp[j],  amp[j1]);
    amp[j]  = __hfma2(nta, amp[j1], amp[j]);
  }
}

// psi *= exp(i*phi(i)), phi = u + 0.5*(v^2 - A2); INIT writes unit phase
template<int PAT, bool INIT>
__device__ __forceinline__ void featureDiag(float2* amp,
                                            const float* __restrict__ wX,
                                            const float* __restrict__ wA,
                                            const float* __restrict__ cons, int t) {
  float u[NAMP], v[NAMP];
  buildTree<PAT>(wX, cons[0], t, u);
  buildTree<PAT>(wA, cons[1], t, v);
  float A2 = cons[2];
  #pragma unroll
  for (int j = 0; j < NAMP; j++) {
    float phi = u[j] + 0.5f * (v[j] * v[j] - A2);
    float sn, cs; rsincos(phi, &sn, &cs);
    if constexpr (INIT) amp[j] = make_float2(cs, sn);
    else                amp[j] = cphase(amp[j], cs, sn);
  }
}

// psi *= ENT(i)*exp(i*rho(i)) on PAT2 (window {0,1,10,11,12}); product tree
// split 16+16 to cap live registers (R11 spill lesson; R11-verified math)
__device__ __forceinline__ void applyDiagPT2(float2* amp,
                                             const float* __restrict__ wb,
                                             const float* __restrict__ eR,
                                             const float* __restrict__ eI,
                                             float bias, int t) {
  float base = bias;
  #pragma unroll
  for (int k = 0; k < 8; k++) base += ((t >> k) & 1) ? wb[2 + k] : 0.0f;
  float2 c[16];
  { float sn, cs; rsincos(base, &sn, &cs); c[0] = make_float2(cs, sn); }
  constexpr int EB[4] = {0, 1, 10, 11};
  #pragma unroll
  for (int k = 0; k < 4; k++) {
    float2 e = make_float2(eR[EB[k]], eI[EB[k]]);
    #pragma unroll
    for (int m = 0; m < (1 << k); m++) c[m | (1 << k)] = cmul(c[m], e);
  }
  #pragma unroll
  for (int j = 0; j < 16; j++) {
    int i = ampIndex<2>(t, j);
    float sgn = (__popc(i & (i >> 1)) & 1) ? -1.0f : 1.0f;
    amp[j] = cphase(amp[j], c[j].x * sgn, c[j].y * sgn);
  }
  float2 e4 = make_float2(eR[12], eI[12]);
  #pragma unroll
  for (int j = 16; j < 32; j++) {
    int i = ampIndex<2>(t, j);
    float sgn = (__popc(i & (i >> 1)) & 1) ? -1.0f : 1.0f;
    float2 cc = cmul(c[j - 16], e4);
    amp[j] = cphase(amp[j], cc.x * sgn, cc.y * sgn);
  }
}

// (256,1): grid pins 2 blocks/CU; lifted VGPR cap avoids the spill cliff.
__global__ __launch_bounds__(NT, 1) void qc_kernel(
    const float* __restrict__ xin,
    const float* __restrict__ thin,
    const float* __restrict__ bin,
    float* __restrict__ out) {
  __shared__ alignas(16) __half2 sAmp[NSLOT];
  __shared__ float gTA[65], gSA[65];      // fp32 shear coeffs (P2/PC fp32 passes)
  __shared__ __half2 hNTA[65], hSA[65];   // packed (-ta,-ta),(sa,sa) (PA/PB)
  __shared__ float gBbit[65];             // b by [l*13 + bitpos], bitpos = 12-q
  __shared__ float eBr[65], eBi[65];      // cos(b), sin(b) by [l*13 + bitpos]
  __shared__ float wX[13], wA[13];        // -2x, -2a by bitpos
  __shared__ float cons[8];               // 0:X 1:A 2:A2 3..7:-0.5*sum b_l
  __shared__ float red[NT / 64];

  const int t = threadIdx.x;
  const int b = blockIdx.x;

  // De-phase co-resident blocks by ~2560 cyc (~half a pass period) so the
  // two blocks on each CU interleave DS-issue and VALU phases instead of
  // contending in lockstep. Keyed on bit0^bit8 to cover both plausible
  // co-residency pairings ({2i,2i+1} sequential, {i,i+256} round-robin).
  // Deterministic, executes identically every call (graph-safe).
  if ((b ^ (b >> 8)) & 1) __builtin_amdgcn_s_sleep(40);

  if (t < NQ) {
    float xq = xin[b * NQ + t];
    float aq = PI_F - xq;
    wX[12 - t] = -2.0f * xq;
    wA[12 - t] = -2.0f * aq;
  }
  if (t < 65) {
    float av = thin[2 * t];
    float bv = thin[2 * t + 1];
    float ca = cosf(0.5f * av);
    float sa = sinf(0.5f * av);
    float ta = sa / (1.0f + ca);
    gTA[t] = ta;
    gSA[t] = sa;
    hNTA[t] = __float2half2_rn(-ta);
    hSA[t]  = __float2half2_rn(sa);
    int l = t / NQ, q = t % NQ;
    int s = l * NQ + (12 - q);
    gBbit[s] = bv;
    eBr[s] = cosf(bv);
    eBi[s] = sinf(bv);
  }
  __syncthreads();
  if (t == 0) {
    float X = 0.f, A = 0.f, A2 = 0.f;
    for (int p = 0; p < NQ; p++) {
      float xq = -0.5f * wX[p], aq = -0.5f * wA[p];
      X += xq; A += aq; A2 += aq * aq;
    }
    cons[0] = X; cons[1] = A; cons[2] = A2;
    for (int l = 0; l < 5; l++) {
      float s = 0.f;
      for (int p = 0; p < NQ; p++) s += gBbit[l * NQ + p];
      cons[3 + l] = -0.5f * s;
    }
  }
  __syncthreads();

  // ---- P0 (PAT0, fp32): init psi = exp(i*phi); FWHT bits 0..4
  {
    float2 amp[NAMP];
    featureDiag<0, true>(amp, wX, wA, cons, t);
    fwht_bit<0>(amp); fwht_bit<1>(amp); fwht_bit<2>(amp);
    fwht_bit<3>(amp); fwht_bit<4>(amp);
    storeA0f(sAmp, t, amp);
  }
  waveFence();   // PAT0->PAT1 wave-private

  // ---- P1 (PAT1, fp16): FWHT bits 5..9
  {
    __half2 amp[NAMP];
    loadA1h(sAmp, t, amp);
    fwht_bitH<0>(amp); fwht_bitH<1>(amp); fwht_bitH<2>(amp);
    fwht_bitH<3>(amp); fwht_bitH<4>(amp);
    storeA1h(sAmp, t, amp);
  }
  __syncthreads();

  // ---- P2 (PAT2, fp32): FWHT bits 10..12; 2nd feature diag; L0 window gates
  {
    float2 amp[NAMP];
    loadA2f(sAmp, t, amp);
    fwht_bit<2>(amp); fwht_bit<3>(amp); fwht_bit<4>(amp);
    featureDiag<2, false>(amp, wX, wA, cons, t);
    applyRy<0>(amp, gTA[12], gSA[12]);
    applyRy<1>(amp, gTA[11], gSA[11]);
    applyRy<2>(amp, gTA[2],  gSA[2]);
    applyRy<3>(amp, gTA[1],  gSA[1]);
    applyRy<4>(amp, gTA[0],  gSA[0]);
    storeA2f(sAmp, t, amp);
  }
  __syncthreads();

  // ---- Layers (17-pass schedule): PA 3 gates fp16, PB 5 gates fp16,
  //      PC (l<4): diag_l + L_{l+1} window gates, fp32
  float acc = 0.0f;
  for (int l = 0; l < 5; l++) {
    const int g = l * NQ;
    // PA (PAT0, fp16): reg bits 2,3,4 -> qubits 10,9,8
    {
      __half2 amp[NAMP];
      loadA0h(sAmp, t, amp);
      applyRyH<2>(amp, hNTA[g + 10], hSA[g + 10]);
      applyRyH<3>(amp, hNTA[g + 9],  hSA[g + 9]);
      applyRyH<4>(amp, hNTA[g + 8],  hSA[g + 8]);
      storeA0h(sAmp, t, amp);
    }
    waveFence();   // PAT0->PAT1 wave-private
    // PB (PAT1, fp16): reg bits 0..4 -> qubits 7..3; l=4 fuses readout
    {
      __half2 amp[NAMP];
      loadA1h(sAmp, t, amp);
      applyRyH<0>(amp, hNTA[g + 7], hSA[g + 7]);
      applyRyH<1>(amp, hNTA[g + 6], hSA[g + 6]);
      applyRyH<2>(amp, hNTA[g + 5], hSA[g + 5]);
      applyRyH<3>(amp, hNTA[g + 4], hSA[g + 4]);
      applyRyH<4>(amp, hNTA[g + 3], hSA[g + 3]);
      if (l < 4) {
        storeA1h(sAmp, t, amp);
      } else {
        // all L4 non-diagonal gates applied; trailing Rz invisible
        #pragma unroll
        for (int j = 0; j < NAMP; j++) {
          int i = ampIndex<1>(t, j);
          float2 a = __half22float2(amp[j]);
          float p2 = fmaf(a.x, a.x, a.y * a.y);
          acc += (__popc(i) & 1) ? -p2 : p2;
        }
      }
    }
    if (l < 4) {
      __syncthreads();
      // PC (PAT2, fp32): diag_l (Rz_l+ENT) then L_{l+1} window gates
      const int g1 = (l + 1) * NQ;
      float2 amp[NAMP];
      loadA2f(sAmp, t, amp);
      applyDiagPT2(amp, gBbit + l * NQ, eBr + l * NQ, eBi + l * NQ,
                   cons[3 + l], t);
      applyRy<0>(amp, gTA[g1 + 12], gSA[g1 + 12]);
      applyRy<1>(amp, gTA[g1 + 11], gSA[g1 + 11]);
      applyRy<2>(amp, gTA[g1 + 2],  gSA[g1 + 2]);
      applyRy<3>(amp, gTA[g1 + 1],  gSA[g1 + 1]);
      applyRy<4>(amp, gTA[g1 + 0],  gSA[g1 + 0]);
      storeA2f(sAmp, t, amp);
      __syncthreads();
    }
  }

  // block reduction (raw scale 2^26)
  #pragma unroll
  for (int off = 32; off > 0; off >>= 1) acc += __shfl_down(acc, off, 64);
  if ((t & 63) == 0) red[t >> 6] = acc;
  __syncthreads();
  if (t == 0) {
    float total = red[0] + red[1] + red[2] + red[3];
    float logit = total * (1.0f / 67108864.0f) + bin[0];
    out[b * 2 + 0] = -logit;
    out[b * 2 + 1] = logit;
  }
}

extern "C" void kernel_launch(void* const* d_in, const int* in_sizes, int n_in,
                              void* d_out, int out_size, void* d_ws, size_t ws_size,
                              hipStream_t stream) {
  const float* x  = (const float*)d_in[0];
  const float* th = (const float*)d_in[1];
  const float* bi = (const float*)d_in[2];
  float* out = (float*)d_out;
  int B = in_sizes[0] / NQ;   // 512
  qc_kernel<<<B, NT, 0, stream>>>(x, th, bi, out);
}

// Round 16
// 89.116 us; speedup vs baseline: 1.0110x; 1.0110x over previous
//
#include <hip/hip_runtime.h>
#include <hip/hip_fp16.h>

#define NQ   13
#define DIM  8192
#define PI_F 3.14159265358979323846f
#define NT   256     // 4 waves/block; grid 512 -> 2 blocks/CU (grid-pinned)
#define NAMP 32      // amplitudes per thread (5-bit register window)

// fp16 state in LDS, pad +4 slots per 32: PAT0/PAT2 runs 16B-aligned for
// ds_*_b128, all patterns at the bank data floor (R13-verified).
__device__ __forceinline__ int lslot(int i) { return i + 4 * (i >> 5); }
#define NSLOT (DIM + 4 * (DIM >> 5))   // 9216 half2 slots = 36.9 KB

__device__ __forceinline__ int base0(int t) { return 36 * t; }
__device__ __forceinline__ int base2(int t, int g) { return 1152 * g + 4 * t + 4 * (t >> 3); }
__device__ __forceinline__ int slot1(int t, int j) { return 1152 * (t >> 5) + 36 * j + (t & 31); }

union F4H { float4 f; __half2 h[4]; };

__device__ __forceinline__ void rsincos(float x, float* s, float* c) {
  const float INV2PI = 0.15915494309189535f;
  const float TWOPI  = 6.283185307179586f;
  float r = x * INV2PI;
  r -= rintf(r);
  float ang = r * TWOPI;
  *s = __sinf(ang);
  *c = __cosf(ang);
}

// wave-local "barrier" (PAT0<->PAT1 both pin i-bits 11,12 to the wave id)
__device__ __forceinline__ void waveFence() {
  __builtin_amdgcn_wave_barrier();
  __threadfence_block();
  __builtin_amdgcn_wave_barrier();
}

// ---- fp32 helpers
__device__ __forceinline__ float2 f2fma(float s, float2 a, float2 b) {
  return make_float2(fmaf(s, a.x, b.x), fmaf(s, a.y, b.y));
}
__device__ __forceinline__ float2 f2add(float2 a, float2 b) {
  return make_float2(a.x + b.x, a.y + b.y);
}
__device__ __forceinline__ float2 f2sub(float2 a, float2 b) {
  return make_float2(a.x - b.x, a.y - b.y);
}
__device__ __forceinline__ float2 cphase(float2 v, float cs, float sn) {
  return make_float2(fmaf(cs, v.x, -sn * v.y), fmaf(cs, v.y, sn * v.x));
}
__device__ __forceinline__ float2 cmul(float2 a, float2 b) {
  return make_float2(fmaf(a.x, b.x, -a.y * b.y), fmaf(a.x, b.y, a.y * b.x));
}

template<int PAT>
__device__ __forceinline__ int ampIndex(int t, int j) {
  if constexpr (PAT == 0) return (t << 5) | j;
  else if constexpr (PAT == 1) return ((t >> 5) << 10) | (j << 5) | (t & 31);
  else return ((j >> 2) << 10) | (t << 2) | (j & 3);
}

// phase tree: s[j] = bias + sum over set bits of i(t,j) of w[bitpos]
template<int PAT>
__device__ __forceinline__ void buildTree(const float* __restrict__ w, float bias,
                                          int t, float* s) {
  float base = bias;
  if constexpr (PAT == 0) {
    #pragma unroll
    for (int k = 0; k < 8; k++) base += ((t >> k) & 1) ? w[5 + k] : 0.0f;
  } else {   // PAT2
    #pragma unroll
    for (int k = 0; k < 8; k++) base += ((t >> k) & 1) ? w[2 + k] : 0.0f;
  }
  constexpr int P[5] = { 0, 1,
                         (PAT == 0) ? 2 : 10,
                         (PAT == 0) ? 3 : 11,
                         (PAT == 0) ? 4 : 12 };
  s[0] = base;
  #pragma unroll
  for (int k = 0; k < 5; k++) {
    float wp = w[P[k]];
    #pragma unroll
    for (int m = 0; m < (1 << k); m++) s[m | (1 << k)] = s[m] + wp;
  }
}

// ---- fp32-register LDS access (b128 packed fp16 at the boundary)
__device__ __forceinline__ void loadA0f(const __half2* __restrict__ sAmp, int t, float2* amp) {
  const __half2* p = sAmp + base0(t);
  #pragma unroll
  for (int k = 0; k < 8; k++) {
    F4H u; u.f = *reinterpret_cast<const float4*>(p + 4 * k);
    #pragma unroll
    for (int c = 0; c < 4; c++) amp[4 * k + c] = __half22float2(u.h[c]);
  }
}
__device__ __forceinline__ void storeA0f(__half2* __restrict__ sAmp, int t, const float2* amp) {
  __half2* p = sAmp + base0(t);
  #pragma unroll
  for (int k = 0; k < 8; k++) {
    F4H u;
    #pragma unroll
    for (int c = 0; c < 4; c++) u.h[c] = __float22half2_rn(amp[4 * k + c]);
    *reinterpret_cast<float4*>(p + 4 * k) = u.f;
  }
}
__device__ __forceinline__ void loadA2f(const __half2* __restrict__ sAmp, int t, float2* amp) {
  #pragma unroll
  for (int g = 0; g < 8; g++) {
    F4H u; u.f = *reinterpret_cast<const float4*>(sAmp + base2(t, g));
    #pragma unroll
    for (int c = 0; c < 4; c++) amp[4 * g + c] = __half22float2(u.h[c]);
  }
}
__device__ __forceinline__ void storeA2f(__half2* __restrict__ sAmp, int t, const float2* amp) {
  #pragma unroll
  for (int g = 0; g < 8; g++) {
    F4H u;
    #pragma unroll
    for (int c = 0; c < 4; c++) u.h[c] = __float22half2_rn(amp[4 * g + c]);
    *reinterpret_cast<float4*>(sAmp + base2(t, g)) = u.f;
  }
}

// ---- fp16-register LDS access
__device__ __forceinline__ void loadA0h(const __half2* __restrict__ sAmp, int t, __half2* amp) {
  const __half2* p = sAmp + base0(t);
  #pragma unroll
  for (int k = 0; k < 8; k++) {
    F4H u; u.f = *reinterpret_cast<const float4*>(p + 4 * k);
    #pragma unroll
    for (int c = 0; c < 4; c++) amp[4 * k + c] = u.h[c];
  }
}
__device__ __forceinline__ void storeA0h(__half2* __restrict__ sAmp, int t, const __half2* amp) {
  __half2* p = sAmp + base0(t);
  #pragma unroll
  for (int k = 0; k < 8; k++) {
    F4H u;
    #pragma unroll
    for (int c = 0; c < 4; c++) u.h[c] = amp[4 * k + c];
    *reinterpret_cast<float4*>(p + 4 * k) = u.f;
  }
}
__device__ __forceinline__ void loadA1h(const __half2* __restrict__ sAmp, int t, __half2* amp) {
  #pragma unroll
  for (int j = 0; j < NAMP; j++) amp[j] = sAmp[slot1(t, j)];
}
__device__ __forceinline__ void storeA1h(__half2* __restrict__ sAmp, int t, const __half2* amp) {
  #pragma unroll
  for (int j = 0; j < NAMP; j++) sAmp[slot1(t, j)] = amp[j];
}

// ---- fp32 gate math
template<int KB>
__device__ __forceinline__ void fwht_bit(float2* amp) {
  #pragma unroll
  for (int j = 0; j < NAMP; j++) if (!(j & (1 << KB))) {
    int j1 = j | (1 << KB);
    float2 a0 = amp[j], a1 = amp[j1];
    amp[j]  = f2add(a0, a1);
    amp[j1] = f2sub(a0, a1);
  }
}
template<int KB>
__device__ __forceinline__ void applyRy(float2* amp, float ta, float sa) {
  #pragma unroll
  for (int j = 0; j < NAMP; j++) if (!(j & (1 << KB))) {
    int j1 = j | (1 << KB);
    amp[j]  = f2fma(-ta, amp[j1], amp[j]);
    amp[j1] = f2fma( sa, amp[j],  amp[j1]);
    amp[j]  = f2fma(-ta, amp[j1], amp[j]);
  }
}

// ---- fp16 packed gate math (v_pk_*_f16)
template<int KB>
__device__ __forceinline__ void fwht_bitH(__half2* amp) {
  #pragma unroll
  for (int j = 0; j < NAMP; j++) if (!(j & (1 << KB))) {
    int j1 = j | (1 << KB);
    __half2 a0 = amp[j], a1 = amp[j1];
    amp[j]  = __hadd2(a0, a1);
    amp[j1] = __hsub2(a0, a1);
  }
}
template<int KB>
__device__ __forceinline__ void applyRyH(__half2* amp, __half2 nta, __half2 sa) {
  #pragma unroll
  for (int j = 0; j < NAMP; j++) if (!(j & (1 << KB))) {
    int j1 = j | (1 << KB);
    amp[j]  = __hfma2(nta, amp[j1], amp[j]);
    amp[j1] = __hfma2(sa,  amp[j],  amp[j1]);
    amp[j]  = __hfma2(nta, amp[j1], amp[j]);
  }
}

// psi *= exp(i*phi(i)), phi = u + 0.5*(v^2 - A2); INIT writes unit phase
template<int PAT, bool INIT>
__device__ __forceinline__ void featureDiag(float2* amp,
                                            const float* __restrict__ wX,
                                            const float* __restrict__ wA,
                                            const float* __restrict__ cons, int t) {
  float u[NAMP], v[NAMP];
  buildTree<PAT>(wX, cons[0], t, u);
  buildTree<PAT>(wA, cons[1], t, v);
  float A2 = cons[2];
  #pragma unroll
  for (int j = 0; j < NAMP; j++) {
    float phi = u[j] + 0.5f * (v[j] * v[j] - A2);
    float sn, cs; rsincos(phi, &sn, &cs);
    if constexpr (INIT) amp[j] = make_float2(cs, sn);
    else                amp[j] = cphase(amp[j], cs, sn);
  }
}

// psi *= ENT(i)*exp(i*rho(i)) on PAT2 (window {0,1,10,11,12}); product tree
// split 16+16 to cap live registers (R11 spill lesson; R11-verified math)
__device__ __forceinline__ void applyDiagPT2(float2* amp,
                                             const float* __restrict__ wb,
                                             const float* __restrict__ eR,
                                             const float* __restrict__ eI,
                                             float bias, int t) {
  float base = bias;
  #pragma unroll
  for (int k = 0; k < 8; k++) base += ((t >> k) & 1) ? wb[2 + k] : 0.0f;
  float2 c[16];
  { float sn, cs; rsincos(base, &sn, &cs); c[0] = make_float2(cs, sn); }
  constexpr int EB[4] = {0, 1, 10, 11};
  #pragma unroll
  for (int k = 0; k < 4; k++) {
    float2 e = make_float2(eR[EB[k]], eI[EB[k]]);
    #pragma unroll
    for (int m = 0; m < (1 << k); m++) c[m | (1 << k)] = cmul(c[m], e);
  }
  #pragma unroll
  for (int j = 0; j < 16; j++) {
    int i = ampIndex<2>(t, j);
    float sgn = (__popc(i & (i >> 1)) & 1) ? -1.0f : 1.0f;
    amp[j] = cphase(amp[j], c[j].x * sgn, c[j].y * sgn);
  }
  float2 e4 = make_float2(eR[12], eI[12]);
  #pragma unroll
  for (int j = 16; j < 32; j++) {
    int i = ampIndex<2>(t, j);
    float sgn = (__popc(i & (i >> 1)) & 1) ? -1.0f : 1.0f;
    float2 cc = cmul(c[j - 16], e4);
    amp[j] = cphase(amp[j], cc.x * sgn, cc.y * sgn);
  }
}

// (256,1): grid pins 2 blocks/CU; lifted VGPR cap avoids the spill cliff.
__global__ __launch_bounds__(NT, 1) void qc_kernel(
    const float* __restrict__ xin,
    const float* __restrict__ thin,
    const float* __restrict__ bin,
    float* __restrict__ out) {
  __shared__ alignas(16) __half2 sAmp[NSLOT];
  __shared__ float gTA[65], gSA[65];      // fp32 shear coeffs (P2/PC fp32 passes)
  __shared__ __half2 hNTA[65], hSA[65];   // packed (-ta,-ta),(sa,sa) (PA/PB)
  __shared__ float gBbit[65];             // b by [l*13 + bitpos], bitpos = 12-q
  __shared__ float eBr[65], eBi[65];      // cos(b), sin(b) by [l*13 + bitpos]
  __shared__ float wX[13], wA[13];        // -2x, -2a by bitpos
  __shared__ float cons[8];               // 0:X 1:A 2:A2 3..7:-0.5*sum b_l
  __shared__ float red[NT / 64];

  const int t = threadIdx.x;
  const int b = blockIdx.x;

  if (t < NQ) {
    float xq = xin[b * NQ + t];
    float aq = PI_F - xq;
    wX[12 - t] = -2.0f * xq;
    wA[12 - t] = -2.0f * aq;
  }
  if (t < 65) {
    float av = thin[2 * t];
    float bv = thin[2 * t + 1];
    float ca = cosf(0.5f * av);
    float sa = sinf(0.5f * av);
    float ta = sa / (1.0f + ca);
    gTA[t] = ta;
    gSA[t] = sa;
    hNTA[t] = __float2half2_rn(-ta);
    hSA[t]  = __float2half2_rn(sa);
    int l = t / NQ, q = t % NQ;
    int s = l * NQ + (12 - q);
    gBbit[s] = bv;
    eBr[s] = cosf(bv);
    eBi[s] = sinf(bv);
  }
  __syncthreads();
  if (t == 0) {
    float X = 0.f, A = 0.f, A2 = 0.f;
    for (int p = 0; p < NQ; p++) {
      float xq = -0.5f * wX[p], aq = -0.5f * wA[p];
      X += xq; A += aq; A2 += aq * aq;
    }
    cons[0] = X; cons[1] = A; cons[2] = A2;
    for (int l = 0; l < 5; l++) {
      float s = 0.f;
      for (int p = 0; p < NQ; p++) s += gBbit[l * NQ + p];
      cons[3 + l] = -0.5f * s;
    }
  }
  __syncthreads();

  // ---- P0 (PAT0, fp32): init psi = exp(i*phi); FWHT bits 0..4
  {
    float2 amp[NAMP];
    featureDiag<0, true>(amp, wX, wA, cons, t);
    fwht_bit<0>(amp); fwht_bit<1>(amp); fwht_bit<2>(amp);
    fwht_bit<3>(amp); fwht_bit<4>(amp);
    storeA0f(sAmp, t, amp);
  }
  waveFence();   // PAT0->PAT1 wave-private

  // ---- P1 (PAT1, fp16): FWHT bits 5..9
  {
    __half2 amp[NAMP];
    loadA1h(sAmp, t, amp);
    fwht_bitH<0>(amp); fwht_bitH<1>(amp); fwht_bitH<2>(amp);
    fwht_bitH<3>(amp); fwht_bitH<4>(amp);
    storeA1h(sAmp, t, amp);
  }
  __syncthreads();

  // ---- P2 (PAT2, fp32): FWHT bits 10..12; 2nd feature diag; L0 window gates
  // (reg bit 0->q12, 1->q11, 2->q2, 3->q1, 4->q0)
  {
    float2 amp[NAMP];
    loadA2f(sAmp, t, amp);
    fwht_bit<2>(amp); fwht_bit<3>(amp); fwht_bit<4>(amp);
    featureDiag<2, false>(amp, wX, wA, cons, t);
    applyRy<0>(amp, gTA[12], gSA[12]);
    applyRy<1>(amp, gTA[11], gSA[11]);
    applyRy<2>(amp, gTA[2],  gSA[2]);
    applyRy<3>(amp, gTA[1],  gSA[1]);
    applyRy<4>(amp, gTA[0],  gSA[0]);
    storeA2f(sAmp, t, amp);
  }
  __syncthreads();

  // ---- Layers (17-pass schedule): PA 3 gates fp16, PB 5 gates fp16,
  //      PC (l<4): diag_l + L_{l+1} window gates, fp32
  float acc = 0.0f;
  for (int l = 0; l < 5; l++) {
    const int g = l * NQ;
    // PA (PAT0, fp16): reg bits 2,3,4 -> qubits 10,9,8
    {
      __half2 amp[NAMP];
      loadA0h(sAmp, t, amp);
      applyRyH<2>(amp, hNTA[g + 10], hSA[g + 10]);
      applyRyH<3>(amp, hNTA[g + 9],  hSA[g + 9]);
      applyRyH<4>(amp, hNTA[g + 8],  hSA[g + 8]);
      storeA0h(sAmp, t, amp);
    }
    waveFence();   // PAT0->PAT1 wave-private
    // PB (PAT1, fp16): reg bits 0..4 -> qubits 7..3; l=4 fuses readout
    {
      __half2 amp[NAMP];
      loadA1h(sAmp, t, amp);
      applyRyH<0>(amp, hNTA[g + 7], hSA[g + 7]);
      applyRyH<1>(amp, hNTA[g + 6], hSA[g + 6]);
      applyRyH<2>(amp, hNTA[g + 5], hSA[g + 5]);
      applyRyH<3>(amp, hNTA[g + 4], hSA[g + 4]);
      applyRyH<4>(amp, hNTA[g + 3], hSA[g + 3]);
      if (l < 4) {
        storeA1h(sAmp, t, amp);
      } else {
        // all L4 non-diagonal gates applied; trailing Rz invisible
        #pragma unroll
        for (int j = 0; j < NAMP; j++) {
          int i = ampIndex<1>(t, j);
          float2 a = __half22float2(amp[j]);
          float p2 = fmaf(a.x, a.x, a.y * a.y);
          acc += (__popc(i) & 1) ? -p2 : p2;
        }
      }
    }
    if (l < 4) {
      __syncthreads();
      // PC (PAT2, fp32): diag_l (Rz_l+ENT) then L_{l+1} window gates
      const int g1 = (l + 1) * NQ;
      float2 amp[NAMP];
      loadA2f(sAmp, t, amp);
      applyDiagPT2(amp, gBbit + l * NQ, eBr + l * NQ, eBi + l * NQ,
                   cons[3 + l], t);
      applyRy<0>(amp, gTA[g1 + 12], gSA[g1 + 12]);
      applyRy<1>(amp, gTA[g1 + 11], gSA[g1 + 11]);
      applyRy<2>(amp, gTA[g1 + 2],  gSA[g1 + 2]);
      applyRy<3>(amp, gTA[g1 + 1],  gSA[g1 + 1]);
      applyRy<4>(amp, gTA[g1 + 0],  gSA[g1 + 0]);
      storeA2f(sAmp, t, amp);
      __syncthreads();
    }
  }

  // block reduction (raw scale 2^26)
  #pragma unroll
  for (int off = 32; off > 0; off >>= 1) acc += __shfl_down(acc, off, 64);
  if ((t & 63) == 0) red[t >> 6] = acc;
  __syncthreads();
  if (t == 0) {
    float total = red[0] + red[1] + red[2] + red[3];
    float logit = total * (1.0f / 67108864.0f) + bin[0];
    out[b * 2 + 0] = -logit;
    out[b * 2 + 1] = logit;
  }
}

extern "C" void kernel_launch(void* const* d_in, const int* in_sizes, int n_in,
                              void* d_out, int out_size, void* d_ws, size_t ws_size,
                              hipStream_t stream) {
  const float* x  = (const float*)d_in[0];
  const float* th = (const float*)d_in[1];
  const float* bi = (const float*)d_in[2];
  float* out = (float*)d_out;
  int B = in_sizes[0] / NQ;   // 512
  qc_kernel<<<B, NT, 0, stream>>>(x, th, bi, out);
}